// Round 12
// baseline (297.992 us; speedup 1.0000x reference)
//
#include <hip/hip_runtime.h>

#define ROW_LEN 128
#define NPAIR (129 * 129)   // (seq, uniq) pairs, each in [0,128]

// Kernel A: precompute MLP(feats(seq,uniq)) for all 16641 pairs -> table[p][32].
__global__ __launch_bounds__(256) void mlp_table_kernel(
    const float* __restrict__ W1, const float* __restrict__ b1,
    const float* __restrict__ W2, const float* __restrict__ b2,
    float* __restrict__ table)
{
    const int tid = blockIdx.x * 256 + threadIdx.x;
    if (tid >= NPAIR * 32) return;
    const int p = tid >> 5;
    const int j = tid & 31;
    const int seq  = p / 129;
    const int uniq = p % 129;
    const float f0 = (float)seq  * (1.0f / 128.0f);
    const float f1 = (float)uniq * (1.0f / 128.0f);
    const float f2 = (seq > 0) ? ((float)uniq / (float)seq) : 0.0f;

    float acc = b2[j];
    #pragma unroll
    for (int jj = 0; jj < 32; ++jj) {
        float h = b1[jj];                 // lane-uniform -> scalar loads
        h = fmaf(f0, W1[jj],      h);
        h = fmaf(f1, W1[32 + jj], h);
        h = fmaf(f2, W1[64 + jj], h);
        h = fmaxf(h, 0.0f);
        acc = fmaf(h, W2[jj * 32 + j], acc);
    }
    table[tid] = fmaxf(acc, 0.0f);
}

// Kernel B (R12): R8's batch-2 double-buffered persistent pipeline +
// __builtin_amdgcn_sched_barrier(0) issue-order fences.
// Evidence chain: R5/R9/R10 show rows/s = waves x rows-per-wave / chain is
// zero-sum while chain stays ~5000 cy (latency-dominated; no pipe >23%).
// R8 tried to pipeline the chain away but VGPR=20 proved hipcc SANK the
// prefetch loads to their uses, deleting the double buffer (the documented
// failure mode: compiler re-schedules source-level pipelines; fix is a
// sched_barrier(0) fence). This kernel is R8 with fences at the three phase
// boundaries of each half-iteration:
//   [issue 2 gathers (prev p) ; issue 4 prefetch loads (next batch)]
//   --fence-- [proc current batch: DS zero/atomic/ballot x2 rows]
//   --fence-- [store gathered prev outputs]  (waits vmcnt(4): gathers are
//   OLDER than prefetches in the in-order queue -> prefetches stay in flight)
//   --fence--
// Verification key: VGPR_Count must rise to >=32 (buffer exists in regs).
__device__ __forceinline__ int proc_row(unsigned* mybm, int lane, int2 id2, int2 mk2)
{
    // re-zero own bitmap: 1024 words = 256 uint4 -> 4 ds_write_b128.
    // Same-wave LDS program order: zero -> atomics -> next row's zero (R5-proven).
    uint4* z = (uint4*)mybm;
    #pragma unroll
    for (int i = 0; i < 4; ++i) z[lane + i * 64] = make_uint4(0u, 0u, 0u, 0u);

    int n0 = 0, n1 = 0;
    if (mk2.x != 0) {
        const unsigned t = (unsigned)id2.x, m = 1u << (t & 31u);
        n0 = ((atomicOr(&mybm[t >> 5], m) & m) == 0u);
    }
    if (mk2.y != 0) {
        const unsigned t = (unsigned)id2.y, m = 1u << (t & 31u);
        n1 = ((atomicOr(&mybm[t >> 5], m) & m) == 0u);
    }
    const unsigned long long s0 = __ballot(mk2.x != 0);
    const unsigned long long s1 = __ballot(mk2.y != 0);
    const unsigned long long u0 = __ballot(n0 != 0);
    const unsigned long long u1 = __ballot(n1 != 0);
    const int seq  = __popcll(s0) + __popcll(s1);
    const int uniq = __popcll(u0) + __popcll(u1);
    return seq * 129 + uniq;
}

__global__ __launch_bounds__(256, 8) void rows_kernel(
    const int* __restrict__ ids, const int* __restrict__ amask,
    const float* __restrict__ table, float* __restrict__ out, int B)
{
    __shared__ unsigned bm[4][1024];   // one 4 KB bitmap per wave
    const int wave = threadIdx.x >> 6;
    const int lane = threadIdx.x & 63;
    unsigned* mybm = bm[wave];
    const int2* ids2 = (const int2*)ids;
    const int2* mk2v = (const int2*)amask;

    const unsigned nw = gridDim.x * 4;             // total waves (8192)
    const unsigned w  = blockIdx.x * 4 + wave;     // wave id
    const unsigned S  = nw * 64;                   // int2-elems per row-step
    const unsigned OS = nw * 32;                   // out-elems per row-step
    // batches only when rows divide evenly (true for B=262144); else tail loop
    const unsigned nb = ((unsigned)B % (2u * nw) == 0u) ? (unsigned)B / (2u * nw) : 0u;

    unsigned li = w * 64 + lane;    // load index, row-step 0 (max 16.7M: fits u32)
    unsigned oi = w * 32 + lane;    // store index, row-step 0

    int2 xi0, xm0, xi1, xm1;        // buffer X (even batches)
    int2 yi0, ym0, yi1, ym1;        // buffer Y (odd batches)
    int p0 = 0, p1 = 0;
    float g0 = 0.0f, g1 = 0.0f;

    if (nb > 0) {
        // prologue: batch 0 -> X, batch 1 -> Y, pinned before proc(batch 0)
        xi0 = ids2[li];          xm0 = mk2v[li];
        xi1 = ids2[li + S];      xm1 = mk2v[li + S];
        if (nb > 1) {
            yi0 = ids2[li + 2 * S]; ym0 = mk2v[li + 2 * S];
            yi1 = ids2[li + 3 * S]; ym1 = mk2v[li + 3 * S];
        }
        unsigned pf = li + 4 * S;   // next prefetch index (row-step 4)
        __builtin_amdgcn_sched_barrier(0);   // pin loads before proc

        p0 = proc_row(mybm, lane, xi0, xm0);
        p1 = proc_row(mybm, lane, xi1, xm1);

        unsigned k = 1;
        for (; k + 1 < nb; k += 2) {
            // ---- batch k (Y); gathers for k-1 issued FIRST (oldest in queue),
            //      then prefetch k+1 -> X; fence; proc; fence; store; fence ----
            if (lane < 32) { g0 = table[p0 * 32 + lane]; g1 = table[p1 * 32 + lane]; }
            xi0 = ids2[pf];     xm0 = mk2v[pf];
            xi1 = ids2[pf + S]; xm1 = mk2v[pf + S];
            pf += 2 * S;
            __builtin_amdgcn_sched_barrier(0);   // pin gather+prefetch issue here
            int q0 = proc_row(mybm, lane, yi0, ym0);
            int q1 = proc_row(mybm, lane, yi1, ym1);
            __builtin_amdgcn_sched_barrier(0);   // proc complete before store
            if (lane < 32) { out[oi] = g0; out[oi + OS] = g1; }  // vmcnt(4): X in flight
            oi += 2 * OS;
            p0 = q0; p1 = q1;
            __builtin_amdgcn_sched_barrier(0);   // phase boundary

            // ---- batch k+1 (X); prefetch k+2 -> Y ----
            if (lane < 32) { g0 = table[p0 * 32 + lane]; g1 = table[p1 * 32 + lane]; }
            if (k + 2 < nb) {
                yi0 = ids2[pf];     ym0 = mk2v[pf];
                yi1 = ids2[pf + S]; ym1 = mk2v[pf + S];
                pf += 2 * S;
            }
            __builtin_amdgcn_sched_barrier(0);
            q0 = proc_row(mybm, lane, xi0, xm0);
            q1 = proc_row(mybm, lane, xi1, xm1);
            __builtin_amdgcn_sched_barrier(0);
            if (lane < 32) { out[oi] = g0; out[oi + OS] = g1; }  // vmcnt(4): Y in flight
            oi += 2 * OS;
            p0 = q0; p1 = q1;
            __builtin_amdgcn_sched_barrier(0);
        }
        if (k < nb) {   // tail batch (odd index -> lives in Y)
            if (lane < 32) { g0 = table[p0 * 32 + lane]; g1 = table[p1 * 32 + lane]; }
            __builtin_amdgcn_sched_barrier(0);
            int q0 = proc_row(mybm, lane, yi0, ym0);
            int q1 = proc_row(mybm, lane, yi1, ym1);
            __builtin_amdgcn_sched_barrier(0);
            if (lane < 32) { out[oi] = g0; out[oi + OS] = g1; }
            oi += 2 * OS;
            p0 = q0; p1 = q1;
        }
        // final gather + store for the last processed batch
        if (lane < 32) {
            out[oi]      = table[p0 * 32 + lane];
            out[oi + OS] = table[p1 * 32 + lane];
        }
    }

    // generic tail (only runs when B % (2*nw) != 0): simple R5-style per row
    for (unsigned row = w + nb * 2 * nw; row < (unsigned)B; row += nw) {
        const unsigned idx = row * 64 + lane;
        const int2 id2 = ids2[idx];
        const int2 mk2 = mk2v[idx];
        const int p = proc_row(mybm, lane, id2, mk2);
        if (lane < 32) out[row * 32 + lane] = table[p * 32 + lane];
    }
}

extern "C" void kernel_launch(void* const* d_in, const int* in_sizes, int n_in,
                              void* d_out, int out_size, void* d_ws, size_t ws_size,
                              hipStream_t stream) {
    const int*   ids   = (const int*)d_in[0];
    const int*   amask = (const int*)d_in[1];
    const float* W1    = (const float*)d_in[2];
    const float* b1    = (const float*)d_in[3];
    const float* W2    = (const float*)d_in[4];
    const float* b2    = (const float*)d_in[5];
    float* out   = (float*)d_out;
    float* table = (float*)d_ws;       // NPAIR*32*4 = 2.13 MB of ws

    const int B = in_sizes[0] / ROW_LEN;              // 262144

    const int tblThreads = NPAIR * 32;
    mlp_table_kernel<<<(tblThreads + 255) / 256, 256, 0, stream>>>(W1, b1, W2, b2, table);

    // persistent grid: 2048 blocks = 8 blocks/CU x 256 CUs; 8192 waves,
    // each wave owns 32 rows = 16 batches of 2, pipelined 2 batches deep.
    int blocks = (B + 3) / 4;
    if (blocks > 2048) blocks = 2048;
    rows_kernel<<<blocks, 256, 0, stream>>>(ids, amask, table, out, B);
}

// Round 13
// 292.780 us; speedup vs baseline: 1.0178x; 1.0178x over previous
//
#include <hip/hip_runtime.h>

#define ROW_LEN 128
#define NPAIR (129 * 129)   // (seq, uniq) pairs, each in [0,128]

// Kernel A: precompute MLP(feats(seq,uniq)) for all 16641 pairs -> table[p][32].
__global__ __launch_bounds__(256) void mlp_table_kernel(
    const float* __restrict__ W1, const float* __restrict__ b1,
    const float* __restrict__ W2, const float* __restrict__ b2,
    float* __restrict__ table)
{
    const int tid = blockIdx.x * 256 + threadIdx.x;
    if (tid >= NPAIR * 32) return;
    const int p = tid >> 5;
    const int j = tid & 31;
    const int seq  = p / 129;
    const int uniq = p % 129;
    const float f0 = (float)seq  * (1.0f / 128.0f);
    const float f1 = (float)uniq * (1.0f / 128.0f);
    const float f2 = (seq > 0) ? ((float)uniq / (float)seq) : 0.0f;

    float acc = b2[j];
    #pragma unroll
    for (int jj = 0; jj < 32; ++jj) {
        float h = b1[jj];                 // lane-uniform -> scalar loads
        h = fmaf(f0, W1[jj],      h);
        h = fmaf(f1, W1[32 + jj], h);
        h = fmaf(f2, W1[64 + jj], h);
        h = fmaxf(h, 0.0f);
        acc = fmaf(h, W2[jj * 32 + j], acc);
    }
    table[tid] = fmaxf(acc, 0.0f);
}

// Kernel B (R13): churn structure, 4 rows per wave, ALL loads issued up front,
// gathers deferred to the end. Straight-line hot path, named scalars only.
// Model (fits R5..R12): delivered BW = inflight-bytes/CU / loaded-latency
// (~2.7us); dur = bytes / BW. R5 holds 1 KB/wave in flight -> 3.2 TB/s.
// Persistent loops (R6/R8/R12) all failed: hipcc sinks loop-carried load
// buffers to their uses (VGPR=20 proves it), and fences can't stop it.
// Churn kernels PROVABLY issue their loads at wave start (R5). So: one wave
// = 4 rows, 8 int2 loads (4 KB) outstanding at once, then 4 sequential
// R5-identical DS phases (rows 1-3's loads complete under row 0's DS work),
// then 2 full-wave gathers + 2 contiguous 256 B stores. The final vmcnt
// wait on gathers drains nothing (row loads long done) - R6's queue-drain
// bug is structurally impossible here.
__device__ __forceinline__ int proc_row(unsigned* mybm, int lane, int2 id2, int2 mk2)
{
    // re-zero own bitmap: 1024 words = 256 uint4 -> 4 ds_write_b128.
    // Same-wave LDS program order: zero -> atomics -> next row's zero (R5-proven).
    uint4* z = (uint4*)mybm;
    #pragma unroll
    for (int i = 0; i < 4; ++i) z[lane + i * 64] = make_uint4(0u, 0u, 0u, 0u);

    int n0 = 0, n1 = 0;
    if (mk2.x != 0) {
        const unsigned t = (unsigned)id2.x, m = 1u << (t & 31u);
        n0 = ((atomicOr(&mybm[t >> 5], m) & m) == 0u);
    }
    if (mk2.y != 0) {
        const unsigned t = (unsigned)id2.y, m = 1u << (t & 31u);
        n1 = ((atomicOr(&mybm[t >> 5], m) & m) == 0u);
    }
    const unsigned long long s0 = __ballot(mk2.x != 0);
    const unsigned long long s1 = __ballot(mk2.y != 0);
    const unsigned long long u0 = __ballot(n0 != 0);
    const unsigned long long u1 = __ballot(n1 != 0);
    const int seq  = __popcll(s0) + __popcll(s1);
    const int uniq = __popcll(u0) + __popcll(u1);
    return seq * 129 + uniq;
}

__global__ __launch_bounds__(256, 8) void rows_kernel(
    const int* __restrict__ ids, const int* __restrict__ amask,
    const float* __restrict__ table, float* __restrict__ out, int B)
{
    __shared__ unsigned bm[4][1024];   // one 4 KB bitmap per wave (16 KB/block)
    const int wave = threadIdx.x >> 6;
    const int lane = threadIdx.x & 63;
    unsigned* mybm = bm[wave];
    const int2* ids2 = (const int2*)ids;
    const int2* mk2v = (const int2*)amask;

    const long rowBase = ((long)blockIdx.x * 4 + wave) * 4;   // 4 rows per wave
    if (rowBase >= B) return;

    if (rowBase + 4 <= (long)B) {
        // ---- hot path: no guards, no arrays -> no spill, no cond-liveness ----
        const long e = rowBase * 64 + lane;   // int2-element index of row 0
        // issue all 8 row loads (4 KB in flight per wave)
        const int2 i0 = ids2[e];        const int2 m0 = mk2v[e];
        const int2 i1 = ids2[e + 64];   const int2 m1 = mk2v[e + 64];
        const int2 i2 = ids2[e + 128];  const int2 m2 = mk2v[e + 128];
        const int2 i3 = ids2[e + 192];  const int2 m3 = mk2v[e + 192];
        __builtin_amdgcn_sched_barrier(0);   // pin: all loads issued before DS work

        // 4 sequential DS phases; rows 1-3's loads land under row 0's phase.
        // Compiler emits decreasing vmcnt waits (only the oldest pair each time).
        const int p0 = proc_row(mybm, lane, i0, m0);
        const int p1 = proc_row(mybm, lane, i1, m1);
        const int p2 = proc_row(mybm, lane, i2, m2);
        const int p3 = proc_row(mybm, lane, i3, m3);

        // epilogue: 2 full-wave gathers (two 128 B L2-hot segments each) +
        // 2 contiguous 256 B stores. lane<32 = even row, lane>=32 = odd row.
        const int pa = (lane < 32) ? p0 : p1;
        const int pb = (lane < 32) ? p2 : p3;
        const int l31 = lane & 31;
        const float ga = table[pa * 32 + l31];
        const float gb = table[pb * 32 + l31];
        const long ob = rowBase * 32 + lane;
        out[ob]      = ga;    // rows 0,1
        out[ob + 64] = gb;    // rows 2,3
    } else {
        // ---- cold tail (never runs for B=262144): simple per-row ----
        for (int j = 0; j < 4; ++j) {
            const long row = rowBase + j;
            if (row >= B) break;
            const long e = row * 64 + lane;
            const int2 id2 = ids2[e];
            const int2 mk2 = mk2v[e];
            const int p = proc_row(mybm, lane, id2, mk2);
            if (lane < 32) out[row * 32 + lane] = table[p * 32 + lane];
        }
    }
}

extern "C" void kernel_launch(void* const* d_in, const int* in_sizes, int n_in,
                              void* d_out, int out_size, void* d_ws, size_t ws_size,
                              hipStream_t stream) {
    const int*   ids   = (const int*)d_in[0];
    const int*   amask = (const int*)d_in[1];
    const float* W1    = (const float*)d_in[2];
    const float* b1    = (const float*)d_in[3];
    const float* W2    = (const float*)d_in[4];
    const float* b2    = (const float*)d_in[5];
    float* out   = (float*)d_out;
    float* table = (float*)d_ws;       // NPAIR*32*4 = 2.13 MB of ws

    const int B = in_sizes[0] / ROW_LEN;              // 262144

    const int tblThreads = NPAIR * 32;
    mlp_table_kernel<<<(tblThreads + 255) / 256, 256, 0, stream>>>(W1, b1, W2, b2, table);

    // 4 rows per wave, 4 waves per block -> 16 rows per block; churn launch
    // (fresh waves' first instructions are their 8 loads = deep natural
    // prefetch, 4 KB outstanding per wave vs R5's 1 KB).
    const long rpb = 16;
    const int blocks = (int)(((long)B + rpb - 1) / rpb);
    rows_kernel<<<blocks, 256, 0, stream>>>(ids, amask, table, out, B);
}

// Round 16
// 291.383 us; speedup vs baseline: 1.0227x; 1.0048x over previous
//
#include <hip/hip_runtime.h>

#define ROW_LEN 128
#define NPAIR (129 * 129)   // (seq, uniq) pairs, each in [0,128]

typedef int v2i __attribute__((ext_vector_type(2)));   // maps to a VGPR pair

// Kernel A: precompute MLP(feats(seq,uniq)) for all 16641 pairs -> table[p][32].
__global__ __launch_bounds__(256) void mlp_table_kernel(
    const float* __restrict__ W1, const float* __restrict__ b1,
    const float* __restrict__ W2, const float* __restrict__ b2,
    float* __restrict__ table)
{
    const int tid = blockIdx.x * 256 + threadIdx.x;
    if (tid >= NPAIR * 32) return;
    const int p = tid >> 5;
    const int j = tid & 31;
    const int seq  = p / 129;
    const int uniq = p % 129;
    const float f0 = (float)seq  * (1.0f / 128.0f);
    const float f1 = (float)uniq * (1.0f / 128.0f);
    const float f2 = (seq > 0) ? ((float)uniq / (float)seq) : 0.0f;

    float acc = b2[j];
    #pragma unroll
    for (int jj = 0; jj < 32; ++jj) {
        float h = b1[jj];                 // lane-uniform -> scalar loads
        h = fmaf(f0, W1[jj],      h);
        h = fmaf(f1, W1[32 + jj], h);
        h = fmaf(f2, W1[64 + jj], h);
        h = fmaxf(h, 0.0f);
        acc = fmaf(h, W2[jj * 32 + j], acc);
    }
    table[tid] = fmaxf(acc, 0.0f);
}

// Kernel B (R14, resubmitted 2x after infra timeouts): churn, 4 rows/wave,
// HAND-WRITTEN load pipeline.
// R8/R12/R13 post-mortems: hipcc's pre-RA scheduler sinks prefetch loads to
// their uses every time (VGPR=20/20/16 prove the buffers never existed);
// sched_barrier alone doesn't stop it. This version issues all 8 row-loads
// in ONE asm volatile block (queue order r0id,r0mk,r1id,...,r3mk) with
// early-clobber VGPR-pair outputs the allocator must keep live, then waits
// with counted s_waitcnt vmcnt(6/4/2/0) + sched_barrier(0) fences (rule #18)
// before each row's DS phase. 4 KB truly in flight per wave; each wait only
// drains the oldest pair. DS phase per row identical to R5 (4x b128 zero,
// 2 atomicOr-rtn, 4 ballots). Epilogue: 2 full-wave gathers + 2 contiguous
// 256 B stores (compiler-managed waits; asm queue already drained).
__device__ __forceinline__ void zero_bm(unsigned* mybm, int lane)
{
    uint4* z = (uint4*)mybm;
    #pragma unroll
    for (int i = 0; i < 4; ++i) z[lane + i * 64] = make_uint4(0u, 0u, 0u, 0u);
}

__device__ __forceinline__ int core_row(unsigned* mybm, v2i id2, v2i mk2)
{
    int n0 = 0, n1 = 0;
    if (mk2[0] != 0) {
        const unsigned t = (unsigned)id2[0], m = 1u << (t & 31u);
        n0 = ((atomicOr(&mybm[t >> 5], m) & m) == 0u);
    }
    if (mk2[1] != 0) {
        const unsigned t = (unsigned)id2[1], m = 1u << (t & 31u);
        n1 = ((atomicOr(&mybm[t >> 5], m) & m) == 0u);
    }
    const unsigned long long s0 = __ballot(mk2[0] != 0);
    const unsigned long long s1 = __ballot(mk2[1] != 0);
    const unsigned long long u0 = __ballot(n0 != 0);
    const unsigned long long u1 = __ballot(n1 != 0);
    const int seq  = __popcll(s0) + __popcll(s1);
    const int uniq = __popcll(u0) + __popcll(u1);
    return seq * 129 + uniq;
}

__global__ __launch_bounds__(256, 8) void rows_kernel(
    const int* __restrict__ ids, const int* __restrict__ amask,
    const float* __restrict__ table, float* __restrict__ out, int B)
{
    __shared__ unsigned bm[4][1024];   // one 4 KB bitmap per wave (16 KB/block)
    const int wave = threadIdx.x >> 6;
    const int lane = threadIdx.x & 63;
    unsigned* mybm = bm[wave];

    const long rowBase = ((long)blockIdx.x * 4 + wave) * 4;   // 4 rows per wave
    if (rowBase >= B) return;

    if (rowBase + 4 <= (long)B) {
        // ---- hot path (always taken for B=262144) ----
        const long e = rowBase * 64 + lane;          // int2-elem index, row 0
        const int2* ia = (const int2*)ids   + e;     // row stride = 64 int2 = 512 B
        const int2* ma = (const int2*)amask + e;

        v2i i0, m0, i1, m1, i2, m2, i3, m3;
        // issue ALL 8 loads, oldest-first; offsets walk rows 1..3 (<4 KB imm).
        asm volatile(
            "global_load_dwordx2 %0, %8, off\n\t"
            "global_load_dwordx2 %1, %9, off\n\t"
            "global_load_dwordx2 %2, %8, off offset:512\n\t"
            "global_load_dwordx2 %3, %9, off offset:512\n\t"
            "global_load_dwordx2 %4, %8, off offset:1024\n\t"
            "global_load_dwordx2 %5, %9, off offset:1024\n\t"
            "global_load_dwordx2 %6, %8, off offset:1536\n\t"
            "global_load_dwordx2 %7, %9, off offset:1536"
            : "=&v"(i0), "=&v"(m0), "=&v"(i1), "=&v"(m1),
              "=&v"(i2), "=&v"(m2), "=&v"(i3), "=&v"(m3)
            : "v"(ia), "v"(ma)
            : "memory");

        // row 0: zero overlaps all 8 loads; wait only the oldest pair
        zero_bm(mybm, lane);
        asm volatile("s_waitcnt vmcnt(6)" ::: "memory");
        __builtin_amdgcn_sched_barrier(0);
        const int p0 = core_row(mybm, i0, m0);

        zero_bm(mybm, lane);          // same-wave DS order: after row0 atomics
        asm volatile("s_waitcnt vmcnt(4)" ::: "memory");
        __builtin_amdgcn_sched_barrier(0);
        const int p1 = core_row(mybm, i1, m1);

        zero_bm(mybm, lane);
        asm volatile("s_waitcnt vmcnt(2)" ::: "memory");
        __builtin_amdgcn_sched_barrier(0);
        const int p2 = core_row(mybm, i2, m2);

        zero_bm(mybm, lane);
        asm volatile("s_waitcnt vmcnt(0)" ::: "memory");
        __builtin_amdgcn_sched_barrier(0);
        const int p3 = core_row(mybm, i3, m3);

        // epilogue: 2 full-wave gathers (two 128 B L2-hot segments each) +
        // 2 contiguous 256 B stores. lane<32 = even row, lane>=32 = odd row.
        const int pa = (lane < 32) ? p0 : p1;
        const int pb = (lane < 32) ? p2 : p3;
        const int l31 = lane & 31;
        const float ga = table[pa * 32 + l31];
        const float gb = table[pb * 32 + l31];
        const long ob = rowBase * 32 + lane;
        out[ob]      = ga;    // rows 0,1
        out[ob + 64] = gb;    // rows 2,3
    } else {
        // ---- cold tail (never runs for B=262144): simple per-row ----
        const int2* ids2 = (const int2*)ids;
        const int2* mk2v = (const int2*)amask;
        for (int j = 0; j < 4; ++j) {
            const long row = rowBase + j;
            if (row >= B) break;
            const long e2 = row * 64 + lane;
            const int2 idp = ids2[e2];
            const int2 mkp = mk2v[e2];
            v2i idv; idv[0] = idp.x; idv[1] = idp.y;
            v2i mkv; mkv[0] = mkp.x; mkv[1] = mkp.y;
            zero_bm(mybm, lane);
            const int p = core_row(mybm, idv, mkv);
            if (lane < 32) out[row * 32 + lane] = table[p * 32 + lane];
        }
    }
}

extern "C" void kernel_launch(void* const* d_in, const int* in_sizes, int n_in,
                              void* d_out, int out_size, void* d_ws, size_t ws_size,
                              hipStream_t stream) {
    const int*   ids   = (const int*)d_in[0];
    const int*   amask = (const int*)d_in[1];
    const float* W1    = (const float*)d_in[2];
    const float* b1    = (const float*)d_in[3];
    const float* W2    = (const float*)d_in[4];
    const float* b2    = (const float*)d_in[5];
    float* out   = (float*)d_out;
    float* table = (float*)d_ws;       // NPAIR*32*4 = 2.13 MB of ws

    const int B = in_sizes[0] / ROW_LEN;              // 262144

    const int tblThreads = NPAIR * 32;
    mlp_table_kernel<<<(tblThreads + 255) / 256, 256, 0, stream>>>(W1, b1, W2, b2, table);

    // 4 rows per wave, 4 waves per block -> 16 rows per block; churn launch.
    // The asm block guarantees 8 loads (4 KB) outstanding per wave at start.
    const long rpb = 16;
    const int blocks = (int)(((long)B + rpb - 1) / rpb);
    rows_kernel<<<blocks, 256, 0, stream>>>(ids, amask, table, out, B);
}